// Round 7
// baseline (298.998 us; speedup 1.0000x reference)
//
#include <hip/hip_runtime.h>

typedef __attribute__((ext_vector_type(8))) short short8;
typedef __attribute__((ext_vector_type(4))) float f32x4;
typedef __attribute__((ext_vector_type(4))) unsigned short u16x4;

#define MFMA_BF16(a, b, c) __builtin_amdgcn_mfma_f32_16x16x32_bf16((a), (b), (c), 0, 0, 0)

__device__ __forceinline__ unsigned short f2bf(float f) {
  unsigned int u = __builtin_bit_cast(unsigned int, f);
  u += 0x7fffu + ((u >> 16) & 1u);
  return (unsigned short)(u >> 16);
}

__device__ __forceinline__ float bf2f(unsigned short s) {
  unsigned int u = ((unsigned int)s) << 16;
  return __builtin_bit_cast(float, u);
}

// async global->LDS, 16 bytes per lane; LDS dest = wave-uniform base + lane*16
__device__ __forceinline__ void gload_lds16(const void* g, void* lds) {
  __builtin_amdgcn_global_load_lds(
      (const __attribute__((address_space(1))) unsigned int*)g,
      (__attribute__((address_space(3))) unsigned int*)lds, 16, 0, 0);
}

// ---------------- cast f32 -> bf16 (vectorized) ----------------
__global__ __launch_bounds__(256) void cast_f32_bf16(const float* __restrict__ src,
                                                     unsigned short* __restrict__ dst, int n4) {
  int i = blockIdx.x * 256 + threadIdx.x;
  if (i >= n4) return;
  float4 v = ((const float4*)src)[i];
  u16x4 r = { f2bf(v.x), f2bf(v.y), f2bf(v.z), f2bf(v.w) };
  ((u16x4*)dst)[i] = r;
}

// ---------------- GEMM (m97 structure): C[M,N] = A[M,K] * W[N,K]^T + bias ----------------
template <int EPI>
__global__ __launch_bounds__(256) void gemm_lds(const unsigned short* __restrict__ A,
                                                const unsigned short* __restrict__ W,
                                                const float* __restrict__ bias,
                                                void* __restrict__ Cout,
                                                int M, int N, int K) {
  __shared__ unsigned short At[128 * 32];
  __shared__ unsigned short Bt[128 * 32];

  const int tid = threadIdx.x;
  const int w = tid >> 6, l = tid & 63;
  const int lr = l & 15, lq = l >> 4;
  const int wr = w >> 1, wc = w & 1;
  const int row0 = blockIdx.x * 128;
  const int col0 = blockIdx.y * 128;

  const int srow = l >> 2;
  const int skoff = (l & 3) * 8;

  f32x4 acc[4][4] = {};

  const unsigned short* Abase = A + (row0 + srow) * (size_t)K + skoff;
  const unsigned short* Bbase = W + (col0 + srow) * (size_t)K + skoff;

  for (int kt = 0; kt < K; kt += 32) {
#pragma unroll
    for (int j = 0; j < 2; j++) {
      const int c = w * 2 + j;
      gload_lds16(Abase + (size_t)(c * 16) * K + kt, &At[c * 512]);
      gload_lds16(Bbase + (size_t)(c * 16) * K + kt, &Bt[c * 512]);
    }
    __syncthreads();

    short8 af[4], bfr[4];
#pragma unroll
    for (int m = 0; m < 4; m++)
      af[m] = *(const short8*)&At[(wr * 64 + m * 16 + lr) * 32 + lq * 8];
#pragma unroll
    for (int n = 0; n < 4; n++)
      bfr[n] = *(const short8*)&Bt[(wc * 64 + n * 16 + lr) * 32 + lq * 8];
#pragma unroll
    for (int m = 0; m < 4; m++)
#pragma unroll
      for (int n = 0; n < 4; n++)
        acc[m][n] = MFMA_BF16(af[m], bfr[n], acc[m][n]);
    __syncthreads();
  }

#pragma unroll
  for (int n = 0; n < 4; n++) {
    const int col = col0 + wc * 64 + n * 16 + lr;
    const float bv = bias[col];
#pragma unroll
    for (int m = 0; m < 4; m++) {
      const int row = row0 + wr * 64 + m * 16 + lq * 4;
#pragma unroll
      for (int r = 0; r < 4; r++) {
        float v = acc[m][n][r] + bv;
        if (EPI == 0) {
          ((unsigned short*)Cout)[(size_t)(row + r) * N + col] = f2bf(v);
        } else if (EPI == 1) {
          ((float*)Cout)[(size_t)(row + r) * N + col] = v;
        } else {
          float g = 0.5f * v * (1.0f + erff(v * 0.70710678118654752f));
          ((float*)Cout)[(size_t)(row + r) * N + col] = g;
        }
      }
    }
  }
}

// ---------------- maskadd (log2 domain): ma[b][k] = mask ? 0 : -1e10*log2e ----------------
__global__ __launch_bounds__(256) void maskadd_kernel(const int* __restrict__ mask,
                                                      float* __restrict__ ma) {
  int i = blockIdx.x * 256 + threadIdx.x;
  if (i < 4096) ma[i] = (mask[i] == 0) ? -1.4426950408889634e10f : 0.0f;
}

// ---------------- V transpose: VT[(bh*64+d)][k] <- v-slab of qkv ----------------
__global__ __launch_bounds__(256) void vtrans_kernel(const unsigned short* __restrict__ qkv,
                                                     unsigned short* __restrict__ VT) {
  const int bh = blockIdx.x;   // 64
  const int kt = blockIdx.y;   // 16 tiles of 64 keys
  const int t = threadIdx.x;
  const int d = t & 63, kg = t >> 6;
  const unsigned short* basev =
      qkv + ((size_t)(bh >> 4) * 1024 + (bh & 15) * 64) * 3072 + 2048;
  const unsigned short* src = basev + (size_t)(kt * 4 + kg) * 3072 + d;
  unsigned short vals[16];
#pragma unroll
  for (int j = 0; j < 16; j++) vals[j] = src[j * 64];
  short8 v0, v1;
#pragma unroll
  for (int j = 0; j < 8; j++) { v0[j] = (short)vals[j]; v1[j] = (short)vals[8 + j]; }
  size_t dst = ((size_t)bh * 64 + d) * 1024 + kt * 64 + kg * 16;
  *(short8*)&VT[dst] = v0;
  *(short8*)&VT[dst + 8] = v1;
}

// ---------------- flash attention v5: K-split (2 splits of 512 keys) ----------------
// 32 q/wave (attn2-proven math), K-only 2-buffer prefetch, V on-demand,
// exp2-domain softmax with LDS-staged scaled mask. Per-split normalized O (bf16)
// + (m,l) per q; combine kernel merges.
struct Kf {
  short8 kf[2][2];   // [key-half][d-chunk]
};

__device__ __forceinline__ void load_k(Kf& f, int kt,
                                       const unsigned short* __restrict__ basek,
                                       int lr, int lq) {
#pragma unroll
  for (int t = 0; t < 2; t++) {
    const unsigned short* ka = basek + (size_t)(kt * 2 + t) * 3072 + lr * 64;
    f.kf[t][0] = *(const short8*)(ka + lq * 8);
    f.kf[t][1] = *(const short8*)(ka + 32 + lq * 8);
  }
}

__device__ __forceinline__ void process(const Kf& f, int kcur, const short8 qf[2][2],
                                        const unsigned short* __restrict__ vtb,
                                        const float* __restrict__ ma_lds,
                                        unsigned short* pw0, unsigned short* pw1,
                                        float m[2], float ll[2], f32x4 o[2][4],
                                        int lr, int lq) {
  constexpr float SC = 0.18033688011112042f;  // 0.125 * log2(e)
  unsigned short* pws[2] = {pw0, pw1};

  // issue V loads early; consumed at PV after ~full softmax latency
  short8 vf[4];
#pragma unroll
  for (int n = 0; n < 4; n++)
    vf[n] = *(const short8*)(vtb + (size_t)(n * 16 + lr) * 1024 + kcur * 32 + lq * 8);

  const float4 mk0 = *(const float4*)&ma_lds[kcur * 32 + lq * 4];
  const float4 mk1 = *(const float4*)&ma_lds[kcur * 32 + 16 + lq * 4];
#pragma unroll
  for (int qt2 = 0; qt2 < 2; qt2++) {
    // S^T tiles: rows = keys (lq*4+r [+16]), cols = q (lr)
    f32x4 s0 = {0.f, 0.f, 0.f, 0.f}, s1 = {0.f, 0.f, 0.f, 0.f};
    s0 = MFMA_BF16(f.kf[0][0], qf[qt2][0], s0);
    s0 = MFMA_BF16(f.kf[0][1], qf[qt2][1], s0);
    s1 = MFMA_BF16(f.kf[1][0], qf[qt2][0], s1);
    s1 = MFMA_BF16(f.kf[1][1], qf[qt2][1], s1);
    float sv[8];
#pragma unroll
    for (int r = 0; r < 4; r++) {
      sv[r]     = s0[r] * SC + ((const float*)&mk0)[r];
      sv[4 + r] = s1[r] * SC + ((const float*)&mk1)[r];
    }
    // online softmax (exp2 domain): state lane-local for q = lr; reduce over lq group
    float t = fmaxf(fmaxf(fmaxf(sv[0], sv[1]), fmaxf(sv[2], sv[3])),
                    fmaxf(fmaxf(sv[4], sv[5]), fmaxf(sv[6], sv[7])));
    t = fmaxf(t, __shfl_xor(t, 16));
    t = fmaxf(t, __shfl_xor(t, 32));
    float mn = fmaxf(m[qt2], t);
    float sc = __builtin_amdgcn_exp2f(m[qt2] - mn);
    m[qt2] = mn;
    float p[8], rs = 0.f;
#pragma unroll
    for (int i = 0; i < 8; i++) { p[i] = __builtin_amdgcn_exp2f(sv[i] - mn); rs += p[i]; }
    rs += __shfl_xor(rs, 16);
    rs += __shfl_xor(rs, 32);
    ll[qt2] = ll[qt2] * sc + rs;
    // pack P (bf16) to per-wave LDS: P[q=lr][k_local], stride 40
    uint2 wa, wb;
    wa.x = (unsigned)f2bf(p[0]) | ((unsigned)f2bf(p[1]) << 16);
    wa.y = (unsigned)f2bf(p[2]) | ((unsigned)f2bf(p[3]) << 16);
    wb.x = (unsigned)f2bf(p[4]) | ((unsigned)f2bf(p[5]) << 16);
    wb.y = (unsigned)f2bf(p[6]) | ((unsigned)f2bf(p[7]) << 16);
    *(uint2*)&pws[qt2][lr * 40 + lq * 4] = wa;
    *(uint2*)&pws[qt2][lr * 40 + 16 + lq * 4] = wb;
    // rescale O (rows q = lq*4+r use sc of lane lq*4+r)
    float scr[4];
#pragma unroll
    for (int r = 0; r < 4; r++) scr[r] = __shfl(sc, lq * 4 + r);
#pragma unroll
    for (int n = 0; n < 4; n++)
#pragma unroll
      for (int r = 0; r < 4; r++) o[qt2][n][r] *= scr[r];
  }
  asm volatile("s_waitcnt lgkmcnt(0)" ::: "memory");
  // PV: A = P[q=lr][k=lq*8..+7] (b128 from LDS), B = V^T frags
#pragma unroll
  for (int qt2 = 0; qt2 < 2; qt2++) {
    const short8 pa = *(const short8*)&pws[qt2][lr * 40 + lq * 8];
#pragma unroll
    for (int n = 0; n < 4; n++)
      o[qt2][n] = MFMA_BF16(pa, vf[n], o[qt2][n]);
  }
}

__global__ __launch_bounds__(256, 4) void attn5_kernel(const unsigned short* __restrict__ qkv,
                                                       const unsigned short* __restrict__ VT,
                                                       const float* __restrict__ maskadd,
                                                       unsigned short* __restrict__ O0,
                                                       unsigned short* __restrict__ O1,
                                                       float2* __restrict__ ML) {
  __shared__ float ma_lds[1024];
  __shared__ unsigned short Pl[4][2][640];  // per wave, per q-tile: [16 q][40]

  const int bh = blockIdx.x, b = bh >> 4, h = bh & 15;
  const int qb = blockIdx.y;      // 0..7
  const int split = blockIdx.z;   // 0..1
  const int k0 = split * 16;      // tile offset (32 keys/tile)
  const int tid = threadIdx.x, w = tid >> 6, l = tid & 63;
  const int lr = l & 15, lq = l >> 4;

  const unsigned short* baseq = qkv + ((size_t)b * 1024 + h * 64) * 3072;
  const unsigned short* basek = baseq + 1024;
  const unsigned short* vtb = VT + (size_t)bh * 64 * 1024;
  unsigned short* opart = split ? O1 : O0;

  // stage scaled mask row into LDS once
  ((float4*)ma_lds)[tid] = ((const float4*)(maskadd + b * 1024))[tid];
  __syncthreads();

  // Q fragments (2 tiles x 2 d-chunks), resident all kernel
  short8 qf[2][2];
  const int q0 = qb * 128 + w * 32;
#pragma unroll
  for (int t = 0; t < 2; t++) {
    int p = q0 + t * 16 + lr;
    const unsigned short* qa = baseq + (p >> 4) * 3072 + (p & 15) * 64;
    qf[t][0] = *(const short8*)(qa + lq * 8);
    qf[t][1] = *(const short8*)(qa + 32 + lq * 8);
  }

  float m[2] = {-1e30f, -1e30f}, ll[2] = {0.f, 0.f};
  f32x4 o[2][4] = {};

  unsigned short* pw0 = &Pl[w][0][0];
  unsigned short* pw1 = &Pl[w][1][0];

  // K-only 2-buffer prefetch over this split's 16 tiles
  Kf fa, fb;
  load_k(fa, k0, basek, lr, lq);
#pragma unroll 1
  for (int lt = 0; lt < 16; lt += 2) {
    load_k(fb, k0 + ((lt + 1) & 15), basek, lr, lq);
    process(fa, k0 + lt, qf, vtb, ma_lds, pw0, pw1, m, ll, o, lr, lq);
    load_k(fa, k0 + ((lt + 2) & 15), basek, lr, lq);
    process(fb, k0 + lt + 1, qf, vtb, ma_lds, pw0, pw1, m, ll, o, lr, lq);
  }

  // epilogue: per-split normalized O (bf16) + (m,l) per q
#pragma unroll
  for (int qt2 = 0; qt2 < 2; qt2++) {
    float inv[4];
#pragma unroll
    for (int r = 0; r < 4; r++) inv[r] = 1.0f / __shfl(ll[qt2], lq * 4 + r);
#pragma unroll
    for (int r = 0; r < 4; r++) {
      int q = q0 + qt2 * 16 + lq * 4 + r;
      size_t obase = ((size_t)b * 1024 + q) * 1024 + h * 64;
#pragma unroll
      for (int n = 0; n < 4; n++)
        opart[obase + n * 16 + lr] = f2bf(o[qt2][n][r] * inv[r]);
    }
  }
  if (l < 16) {
    float2* mlrow = ML + ((size_t)split * 64 + bh) * 1024;
#pragma unroll
    for (int qt2 = 0; qt2 < 2; qt2++) {
      int q = q0 + qt2 * 16 + l;
      mlrow[q] = float2{m[qt2], ll[qt2]};
    }
  }
}

// ---------------- combine the two K-splits ----------------
__global__ __launch_bounds__(256) void combine_kernel(const unsigned short* __restrict__ O0,
                                                      const unsigned short* __restrict__ O1,
                                                      const float2* __restrict__ ML,
                                                      unsigned short* __restrict__ att) {
  const int row = blockIdx.x;          // b*1024 + q
  const int t = threadIdx.x;
  const int col = t * 4;
  const int b = row >> 10, q = row & 1023;
  const int h = col >> 6;
  const int bh = b * 16 + h;
  const float2 ml0 = ML[(size_t)bh * 1024 + q];
  const float2 ml1 = ML[((size_t)64 + bh) * 1024 + q];
  const float M = fmaxf(ml0.x, ml1.x);
  float w0 = __builtin_amdgcn_exp2f(ml0.x - M) * ml0.y;
  float w1 = __builtin_amdgcn_exp2f(ml1.x - M) * ml1.y;
  const float inv = 1.0f / (w0 + w1);
  w0 *= inv; w1 *= inv;
  const size_t base = (size_t)row * 1024 + col;
  u16x4 a = *(const u16x4*)&O0[base];
  u16x4 c = *(const u16x4*)&O1[base];
  u16x4 r;
#pragma unroll
  for (int j = 0; j < 4; j++)
    r[j] = f2bf(bf2f(a[j]) * w0 + bf2f(c[j]) * w1);
  *(u16x4*)&att[base] = r;
}

// ---------------- LayerNorm kernels (fp32, E=1024, one row per block) ----------------
__global__ __launch_bounds__(256) void ln1_kernel(const float* __restrict__ x,
                                                  const float* __restrict__ attp,
                                                  const float* __restrict__ g,
                                                  const float* __restrict__ bt,
                                                  float* __restrict__ sf,
                                                  unsigned short* __restrict__ sb) {
  const int row = blockIdx.x, tid = threadIdx.x;
  float4 xv = ((const float4*)(x + row * 1024))[tid];
  float4 av = ((const float4*)(attp + row * 1024))[tid];
  float4 v = {xv.x + av.x, xv.y + av.y, xv.z + av.z, xv.w + av.w};
  float s = v.x + v.y + v.z + v.w;
  float sq = v.x * v.x + v.y * v.y + v.z * v.z + v.w * v.w;
#pragma unroll
  for (int off = 1; off < 64; off <<= 1) { s += __shfl_xor(s, off); sq += __shfl_xor(sq, off); }
  __shared__ float ws[8];
  int wv = tid >> 6, l = tid & 63;
  if (l == 0) { ws[wv] = s; ws[4 + wv] = sq; }
  __syncthreads();
  s = ws[0] + ws[1] + ws[2] + ws[3];
  sq = ws[4] + ws[5] + ws[6] + ws[7];
  float mean = s * (1.0f / 1024.0f);
  float var = sq * (1.0f / 1024.0f) - mean * mean;
  float rs = rsqrtf(var + 1e-5f);
  float4 gv = ((const float4*)g)[tid];
  float4 bv = ((const float4*)bt)[tid];
  float4 y;
  y.x = (v.x - mean) * rs * gv.x + bv.x;
  y.y = (v.y - mean) * rs * gv.y + bv.y;
  y.z = (v.z - mean) * rs * gv.z + bv.z;
  y.w = (v.w - mean) * rs * gv.w + bv.w;
  ((float4*)(sf + row * 1024))[tid] = y;
  u16x4 yb = { f2bf(y.x), f2bf(y.y), f2bf(y.z), f2bf(y.w) };
  ((u16x4*)(sb + row * 1024))[tid] = yb;
}

__global__ __launch_bounds__(256) void ln2_kernel(const float* __restrict__ skip,
                                                  const float* __restrict__ fcc,
                                                  const float* __restrict__ g,
                                                  const float* __restrict__ bt,
                                                  const float* __restrict__ x,
                                                  const float* __restrict__ alphap,
                                                  float* __restrict__ out) {
  const int row = blockIdx.x, tid = threadIdx.x;
  float4 sv = ((const float4*)(skip + row * 1024))[tid];
  float4 fv = ((const float4*)(fcc + row * 1024))[tid];
  float4 v = {sv.x + fv.x, sv.y + fv.y, sv.z + fv.z, sv.w + fv.w};
  float s = v.x + v.y + v.z + v.w;
  float sq = v.x * v.x + v.y * v.y + v.z * v.z + v.w * v.w;
#pragma unroll
  for (int off = 1; off < 64; off <<= 1) { s += __shfl_xor(s, off); sq += __shfl_xor(sq, off); }
  __shared__ float ws[8];
  int wv = tid >> 6, l = tid & 63;
  if (l == 0) { ws[wv] = s; ws[4 + wv] = sq; }
  __syncthreads();
  s = ws[0] + ws[1] + ws[2] + ws[3];
  sq = ws[4] + ws[5] + ws[6] + ws[7];
  float mean = s * (1.0f / 1024.0f);
  float var = sq * (1.0f / 1024.0f) - mean * mean;
  float rs = rsqrtf(var + 1e-5f);
  float4 gv = ((const float4*)g)[tid];
  float4 bv = ((const float4*)bt)[tid];
  float alpha = alphap[0];
  float beta = 1.0f - alpha;
  float4 xv = ((const float4*)(x + row * 1024))[tid];
  float4 y;
  y.x = xv.x * alpha + ((v.x - mean) * rs * gv.x + bv.x) * beta;
  y.y = xv.y * alpha + ((v.y - mean) * rs * gv.y + bv.y) * beta;
  y.z = xv.z * alpha + ((v.z - mean) * rs * gv.z + bv.z) * beta;
  y.w = xv.w * alpha + ((v.w - mean) * rs * gv.w + bv.w) * beta;
  ((float4*)(out + row * 1024))[tid] = y;
}

// ---------------- launch ----------------
extern "C" void kernel_launch(void* const* d_in, const int* in_sizes, int n_in,
                              void* d_out, int out_size, void* d_ws, size_t ws_size,
                              hipStream_t stream) {
  const float* x  = (const float*)d_in[0];
  const int* mask = (const int*)d_in[1];
  const float* Wq = (const float*)d_in[2];
  const float* bq = (const float*)d_in[3];
  const float* Wk = (const float*)d_in[4];
  const float* bk = (const float*)d_in[5];
  const float* Wv = (const float*)d_in[6];
  const float* bv = (const float*)d_in[7];
  const float* Wo = (const float*)d_in[8];
  const float* bo = (const float*)d_in[9];
  const float* g1 = (const float*)d_in[10];
  const float* b1 = (const float*)d_in[11];
  const float* Wf = (const float*)d_in[12];
  const float* bf = (const float*)d_in[13];
  const float* g2 = (const float*)d_in[14];
  const float* b2 = (const float*)d_in[15];
  const float* alpha = (const float*)d_in[16];
  float* out = (float*)d_out;

  char* ws = (char*)d_ws;
  size_t off = 0;
  unsigned short* xb   = (unsigned short*)(ws + off); off += 8388608;   // 4096x1024 bf16
  unsigned short* Wqkv = (unsigned short*)(ws + off); off += 6291456;   // 3072x1024 bf16
  unsigned short* Wob  = (unsigned short*)(ws + off); off += 2097152;
  unsigned short* Wfb  = (unsigned short*)(ws + off); off += 2097152;
  float* bcat          = (float*)(ws + off);          off += 12288;
  float* maf           = (float*)(ws + off);          off += 16384;     // maskadd [4][1024]
  float2* mlbuf        = (float2*)(ws + off);         off += 1048576;   // (m,l)[2][64][1024]
  unsigned short* qkvb = (unsigned short*)(ws + off); off += 25165824;  // 4096x3072 bf16
  unsigned short* attb = (unsigned short*)(ws + off); off += 8388608;
  float* tmp           = (float*)(ws + off);          off += 16777216;  // VT+Opart1 (attn) -> att@Wo -> fcc
  float* s1f           = (float*)(ws + off);          off += 16777216;
  unsigned short* s1b  = (unsigned short*)(ws + off); off += 8388608;

  unsigned short* VT = (unsigned short*)tmp;                    // 8MB, attn-phase only
  unsigned short* Opart0 = s1b;                                 // 8MB, attn-phase only
  unsigned short* Opart1 = (unsigned short*)(tmp + 2097152);    // tmp second 8MB

  // casts + prep
  cast_f32_bf16<<<4096, 256, 0, stream>>>(x, xb, 1048576);
  cast_f32_bf16<<<1024, 256, 0, stream>>>(Wq, Wqkv, 262144);
  cast_f32_bf16<<<1024, 256, 0, stream>>>(Wk, Wqkv + 1048576, 262144);
  cast_f32_bf16<<<1024, 256, 0, stream>>>(Wv, Wqkv + 2097152, 262144);
  cast_f32_bf16<<<1024, 256, 0, stream>>>(Wo, Wob, 262144);
  cast_f32_bf16<<<1024, 256, 0, stream>>>(Wf, Wfb, 262144);
  maskadd_kernel<<<16, 256, 0, stream>>>(mask, maf);
  hipMemcpyAsync(bcat,        bq, 4096, hipMemcpyDeviceToDevice, stream);
  hipMemcpyAsync(bcat + 1024, bk, 4096, hipMemcpyDeviceToDevice, stream);
  hipMemcpyAsync(bcat + 2048, bv, 4096, hipMemcpyDeviceToDevice, stream);

  // fused QKV GEMM: [4096,1024] x [3072,1024]^T -> bf16 [4096,3072]
  gemm_lds<0><<<dim3(32, 24), 256, 0, stream>>>(xb, Wqkv, bcat, qkvb, 4096, 3072, 1024);

  // V transpose -> VT[(bh*64+d)][k]
  vtrans_kernel<<<dim3(64, 16), 256, 0, stream>>>(qkvb, VT);

  // attention, K-split x2 -> per-split normalized O + (m,l)
  attn5_kernel<<<dim3(64, 8, 2), 256, 0, stream>>>(qkvb, VT, maf, Opart0, Opart1, mlbuf);

  // combine splits -> att bf16 [4096,1024]
  combine_kernel<<<4096, 256, 0, stream>>>(Opart0, Opart1, mlbuf, attb);

  // O projection -> f32 tmp
  gemm_lds<1><<<dim3(32, 8), 256, 0, stream>>>(attb, Wob, bo, tmp, 4096, 1024, 1024);

  // LN1: skip1 = LN(x + tmp); emits f32 + bf16
  ln1_kernel<<<4096, 256, 0, stream>>>(x, tmp, g1, b1, s1f, s1b);

  // FF GEMM + exact GELU -> f32 (reuse tmp)
  gemm_lds<2><<<dim3(32, 8), 256, 0, stream>>>(s1b, Wfb, bf, tmp, 4096, 1024, 1024);

  // LN2 + final mix
  ln2_kernel<<<4096, 256, 0, stream>>>(s1f, tmp, g2, b2, x, alpha, out);
}

// Round 8
// 206.621 us; speedup vs baseline: 1.4471x; 1.4471x over previous
//
#include <hip/hip_runtime.h>

typedef __attribute__((ext_vector_type(8))) short short8;
typedef __attribute__((ext_vector_type(4))) float f32x4;
typedef __attribute__((ext_vector_type(4))) unsigned short u16x4;

#define MFMA_BF16(a, b, c) __builtin_amdgcn_mfma_f32_16x16x32_bf16((a), (b), (c), 0, 0, 0)

__device__ __forceinline__ unsigned short f2bf(float f) {
  unsigned int u = __builtin_bit_cast(unsigned int, f);
  u += 0x7fffu + ((u >> 16) & 1u);
  return (unsigned short)(u >> 16);
}

// async global->LDS, 16 bytes per lane; LDS dest = wave-uniform base + lane*16
__device__ __forceinline__ void gload_lds16(const void* g, void* lds) {
  __builtin_amdgcn_global_load_lds(
      (const __attribute__((address_space(1))) unsigned int*)g,
      (__attribute__((address_space(3))) unsigned int*)lds, 16, 0, 0);
}

// ---------------- fused cast f32 -> bf16 for x + 5 weight matrices ----------------
__global__ __launch_bounds__(256) void cast_all(const float* __restrict__ x,
                                                const float* __restrict__ Wq,
                                                const float* __restrict__ Wk,
                                                const float* __restrict__ Wv,
                                                const float* __restrict__ Wo,
                                                const float* __restrict__ Wf,
                                                unsigned short* __restrict__ xb,
                                                unsigned short* __restrict__ Wqkv,
                                                unsigned short* __restrict__ Wob,
                                                unsigned short* __restrict__ Wfb) {
  int i = blockIdx.x * 256 + threadIdx.x;
  const float* src;
  unsigned short* dst;
  int j;
  if (i < 1048576)      { src = x;  dst = xb;             j = i; }
  else if (i < 1310720) { src = Wq; dst = Wqkv;           j = i - 1048576; }
  else if (i < 1572864) { src = Wk; dst = Wqkv + 1048576; j = i - 1310720; }
  else if (i < 1835008) { src = Wv; dst = Wqkv + 2097152; j = i - 1572864; }
  else if (i < 2097152) { src = Wo; dst = Wob;            j = i - 1835008; }
  else                  { src = Wf; dst = Wfb;            j = i - 2097152; }
  float4 v = ((const float4*)src)[j];
  u16x4 r = { f2bf(v.x), f2bf(v.y), f2bf(v.z), f2bf(v.w) };
  ((u16x4*)dst)[j] = r;
}

// ---------------- GEMM (m97 structure): C[M,N] = A[M,K] * W[N,K]^T + bias ----------------
template <int EPI>
__global__ __launch_bounds__(256) void gemm_lds(const unsigned short* __restrict__ A,
                                                const unsigned short* __restrict__ W,
                                                const float* __restrict__ bias,
                                                void* __restrict__ Cout,
                                                int M, int N, int K) {
  __shared__ unsigned short At[128 * 32];
  __shared__ unsigned short Bt[128 * 32];

  const int tid = threadIdx.x;
  const int w = tid >> 6, l = tid & 63;
  const int lr = l & 15, lq = l >> 4;
  const int wr = w >> 1, wc = w & 1;
  const int row0 = blockIdx.x * 128;
  const int col0 = blockIdx.y * 128;

  const int srow = l >> 2;
  const int skoff = (l & 3) * 8;

  f32x4 acc[4][4] = {};

  const unsigned short* Abase = A + (row0 + srow) * (size_t)K + skoff;
  const unsigned short* Bbase = W + (col0 + srow) * (size_t)K + skoff;

  for (int kt = 0; kt < K; kt += 32) {
#pragma unroll
    for (int j = 0; j < 2; j++) {
      const int c = w * 2 + j;
      gload_lds16(Abase + (size_t)(c * 16) * K + kt, &At[c * 512]);
      gload_lds16(Bbase + (size_t)(c * 16) * K + kt, &Bt[c * 512]);
    }
    __syncthreads();

    short8 af[4], bfr[4];
#pragma unroll
    for (int m = 0; m < 4; m++)
      af[m] = *(const short8*)&At[(wr * 64 + m * 16 + lr) * 32 + lq * 8];
#pragma unroll
    for (int n = 0; n < 4; n++)
      bfr[n] = *(const short8*)&Bt[(wc * 64 + n * 16 + lr) * 32 + lq * 8];
#pragma unroll
    for (int m = 0; m < 4; m++)
#pragma unroll
      for (int n = 0; n < 4; n++)
        acc[m][n] = MFMA_BF16(af[m], bfr[n], acc[m][n]);
    __syncthreads();
  }

#pragma unroll
  for (int n = 0; n < 4; n++) {
    const int col = col0 + wc * 64 + n * 16 + lr;
    const float bv = bias[col];
#pragma unroll
    for (int m = 0; m < 4; m++) {
      const int row = row0 + wr * 64 + m * 16 + lq * 4;
#pragma unroll
      for (int r = 0; r < 4; r++) {
        float v = acc[m][n][r] + bv;
        if (EPI == 0) {
          ((unsigned short*)Cout)[(size_t)(row + r) * N + col] = f2bf(v);
        } else if (EPI == 1) {
          ((float*)Cout)[(size_t)(row + r) * N + col] = v;
        } else {
          float g = 0.5f * v * (1.0f + erff(v * 0.70710678118654752f));
          ((float*)Cout)[(size_t)(row + r) * N + col] = g;
        }
      }
    }
  }
}

// ---------------- maskadd (log2 domain): ma[b][k] = mask ? 0 : -1e10*log2e ----------------
__global__ __launch_bounds__(256) void maskadd_kernel(const int* __restrict__ mask,
                                                      float* __restrict__ ma) {
  int i = blockIdx.x * 256 + threadIdx.x;
  if (i < 4096) ma[i] = (mask[i] == 0) ? -1.4426950408889634e10f : 0.0f;
}

// ---------------- V transpose: VT[(bh*64+d)][k] <- v-slab of qkv ----------------
__global__ __launch_bounds__(256) void vtrans_kernel(const unsigned short* __restrict__ qkv,
                                                     unsigned short* __restrict__ VT) {
  const int bh = blockIdx.x;   // 64
  const int kt = blockIdx.y;   // 16 tiles of 64 keys
  const int t = threadIdx.x;
  const int d = t & 63, kg = t >> 6;
  const unsigned short* basev =
      qkv + ((size_t)(bh >> 4) * 1024 + (bh & 15) * 64) * 3072 + 2048;
  const unsigned short* src = basev + (size_t)(kt * 4 + kg) * 3072 + d;
  unsigned short vals[16];
#pragma unroll
  for (int j = 0; j < 16; j++) vals[j] = src[j * 64];
  short8 v0, v1;
#pragma unroll
  for (int j = 0; j < 8; j++) { v0[j] = (short)vals[j]; v1[j] = (short)vals[8 + j]; }
  size_t dst = ((size_t)bh * 64 + d) * 1024 + kt * 64 + kg * 16;
  *(short8*)&VT[dst] = v0;
  *(short8*)&VT[dst + 8] = v1;
}

// ---------------- flash attention v6 ----------------
// attn2-proven structure (32 q/wave, 2-buffer prefetch, grid (64,8), no VGPR cap)
// + exp2-domain softmax, LDS-staged scaled mask, deferred l-reduction.
struct Frags {
  short8 kf[2][2];   // [key-half][d-chunk]
  short8 vf[4];      // V^T frags per d-tile
};

__device__ __forceinline__ void load_frags(Frags& f, int kt,
                                           const unsigned short* __restrict__ basek,
                                           const unsigned short* __restrict__ vtb,
                                           int lr, int lq) {
#pragma unroll
  for (int t = 0; t < 2; t++) {
    const unsigned short* ka = basek + (size_t)(kt * 2 + t) * 3072 + lr * 64;
    f.kf[t][0] = *(const short8*)(ka + lq * 8);
    f.kf[t][1] = *(const short8*)(ka + 32 + lq * 8);
  }
#pragma unroll
  for (int n = 0; n < 4; n++)
    f.vf[n] = *(const short8*)(vtb + (size_t)(n * 16 + lr) * 1024 + kt * 32 + lq * 8);
}

__device__ __forceinline__ void process(const Frags& f, int kcur, const short8 qf[2][2],
                                        const float* __restrict__ ma_lds,
                                        unsigned short* pw0, unsigned short* pw1,
                                        float m[2], float ll[2], f32x4 o[2][4],
                                        int lr, int lq) {
  constexpr float SC = 0.18033688011112042f;  // 0.125 * log2(e)
  unsigned short* pws[2] = {pw0, pw1};
  const float4 mk0 = *(const float4*)&ma_lds[kcur * 32 + lq * 4];
  const float4 mk1 = *(const float4*)&ma_lds[kcur * 32 + 16 + lq * 4];
#pragma unroll
  for (int qt2 = 0; qt2 < 2; qt2++) {
    // S^T tiles: rows = keys (lq*4+r [+16]), cols = q (lr)
    f32x4 s0 = {0.f, 0.f, 0.f, 0.f}, s1 = {0.f, 0.f, 0.f, 0.f};
    s0 = MFMA_BF16(f.kf[0][0], qf[qt2][0], s0);
    s0 = MFMA_BF16(f.kf[0][1], qf[qt2][1], s0);
    s1 = MFMA_BF16(f.kf[1][0], qf[qt2][0], s1);
    s1 = MFMA_BF16(f.kf[1][1], qf[qt2][1], s1);
    float sv[8];
#pragma unroll
    for (int r = 0; r < 4; r++) {
      sv[r]     = s0[r] * SC + ((const float*)&mk0)[r];
      sv[4 + r] = s1[r] * SC + ((const float*)&mk1)[r];
    }
    // online softmax (exp2 domain): state lane-local for q = lr; max over lq group
    float t = fmaxf(fmaxf(fmaxf(sv[0], sv[1]), fmaxf(sv[2], sv[3])),
                    fmaxf(fmaxf(sv[4], sv[5]), fmaxf(sv[6], sv[7])));
    t = fmaxf(t, __shfl_xor(t, 16));
    t = fmaxf(t, __shfl_xor(t, 32));
    float mn = fmaxf(m[qt2], t);
    float sc = __builtin_amdgcn_exp2f(m[qt2] - mn);
    m[qt2] = mn;
    float p[8], rs = 0.f;
#pragma unroll
    for (int i = 0; i < 8; i++) { p[i] = __builtin_amdgcn_exp2f(sv[i] - mn); rs += p[i]; }
    // deferred l-reduction: ll stays lane-partial (this lane's 8 keys); sc is group-uniform
    ll[qt2] = ll[qt2] * sc + rs;
    // pack P (bf16) to per-wave LDS: P[q=lr][k_local], stride 40
    uint2 wa, wb;
    wa.x = (unsigned)f2bf(p[0]) | ((unsigned)f2bf(p[1]) << 16);
    wa.y = (unsigned)f2bf(p[2]) | ((unsigned)f2bf(p[3]) << 16);
    wb.x = (unsigned)f2bf(p[4]) | ((unsigned)f2bf(p[5]) << 16);
    wb.y = (unsigned)f2bf(p[6]) | ((unsigned)f2bf(p[7]) << 16);
    *(uint2*)&pws[qt2][lr * 40 + lq * 4] = wa;
    *(uint2*)&pws[qt2][lr * 40 + 16 + lq * 4] = wb;
    // rescale O (rows q = lq*4+r use sc of lane lq*4+r)
    float scr[4];
#pragma unroll
    for (int r = 0; r < 4; r++) scr[r] = __shfl(sc, lq * 4 + r);
#pragma unroll
    for (int n = 0; n < 4; n++)
#pragma unroll
      for (int r = 0; r < 4; r++) o[qt2][n][r] *= scr[r];
  }
  asm volatile("s_waitcnt lgkmcnt(0)" ::: "memory");
  // PV: A = P[q=lr][k=lq*8..+7] (b128 from LDS), B = V^T frags
#pragma unroll
  for (int qt2 = 0; qt2 < 2; qt2++) {
    const short8 pa = *(const short8*)&pws[qt2][lr * 40 + lq * 8];
#pragma unroll
    for (int n = 0; n < 4; n++)
      o[qt2][n] = MFMA_BF16(pa, f.vf[n], o[qt2][n]);
  }
}

__global__ __launch_bounds__(256) void attn6_kernel(const unsigned short* __restrict__ qkv,
                                                    const unsigned short* __restrict__ VT,
                                                    const float* __restrict__ maskadd,
                                                    unsigned short* __restrict__ att) {
  __shared__ float ma_lds[1024];
  __shared__ unsigned short Pl[4][2][640];  // per wave, per q-tile: [16 q][40]

  const int bh = blockIdx.x, b = bh >> 4, h = bh & 15;
  const int qb = blockIdx.y;
  const int tid = threadIdx.x, w = tid >> 6, l = tid & 63;
  const int lr = l & 15, lq = l >> 4;

  const unsigned short* baseq = qkv + ((size_t)b * 1024 + h * 64) * 3072;
  const unsigned short* basek = baseq + 1024;
  const unsigned short* vtb = VT + (size_t)bh * 64 * 1024;

  // stage scaled mask row into LDS once
  ((float4*)ma_lds)[tid] = ((const float4*)(maskadd + b * 1024))[tid];
  __syncthreads();

  // Q fragments (2 tiles x 2 d-chunks), resident all kernel
  short8 qf[2][2];
  const int q0 = qb * 128 + w * 32;
#pragma unroll
  for (int t = 0; t < 2; t++) {
    int p = q0 + t * 16 + lr;
    const unsigned short* qa = baseq + (p >> 4) * 3072 + (p & 15) * 64;
    qf[t][0] = *(const short8*)(qa + lq * 8);
    qf[t][1] = *(const short8*)(qa + 32 + lq * 8);
  }

  float m[2] = {-1e30f, -1e30f}, ll[2] = {0.f, 0.f};
  f32x4 o[2][4] = {};

  unsigned short* pw0 = &Pl[w][0][0];
  unsigned short* pw1 = &Pl[w][1][0];

  Frags fa, fb;
  load_frags(fa, 0, basek, vtb, lr, lq);
#pragma unroll 1
  for (int kt = 0; kt < 32; kt += 2) {
    load_frags(fb, (kt + 1) & 31, basek, vtb, lr, lq);
    process(fa, kt, qf, ma_lds, pw0, pw1, m, ll, o, lr, lq);
    load_frags(fa, (kt + 2) & 31, basek, vtb, lr, lq);
    process(fb, kt + 1, qf, ma_lds, pw0, pw1, m, ll, o, lr, lq);
  }

  // epilogue: finish deferred l-reduction, normalize, write att[b, q, h*64 + d]
#pragma unroll
  for (int qt2 = 0; qt2 < 2; qt2++) {
    float lf = ll[qt2];
    lf += __shfl_xor(lf, 16);
    lf += __shfl_xor(lf, 32);
    float inv[4];
#pragma unroll
    for (int r = 0; r < 4; r++) inv[r] = 1.0f / __shfl(lf, lq * 4 + r);
#pragma unroll
    for (int r = 0; r < 4; r++) {
      int q = q0 + qt2 * 16 + lq * 4 + r;
      size_t obase = ((size_t)b * 1024 + q) * 1024 + h * 64;
#pragma unroll
      for (int n = 0; n < 4; n++)
        att[obase + n * 16 + lr] = f2bf(o[qt2][n][r] * inv[r]);
    }
  }
}

// ---------------- LayerNorm kernels (fp32, E=1024, one row per block) ----------------
__global__ __launch_bounds__(256) void ln1_kernel(const float* __restrict__ x,
                                                  const float* __restrict__ attp,
                                                  const float* __restrict__ g,
                                                  const float* __restrict__ bt,
                                                  float* __restrict__ sf,
                                                  unsigned short* __restrict__ sb) {
  const int row = blockIdx.x, tid = threadIdx.x;
  float4 xv = ((const float4*)(x + row * 1024))[tid];
  float4 av = ((const float4*)(attp + row * 1024))[tid];
  float4 v = {xv.x + av.x, xv.y + av.y, xv.z + av.z, xv.w + av.w};
  float s = v.x + v.y + v.z + v.w;
  float sq = v.x * v.x + v.y * v.y + v.z * v.z + v.w * v.w;
#pragma unroll
  for (int off = 1; off < 64; off <<= 1) { s += __shfl_xor(s, off); sq += __shfl_xor(sq, off); }
  __shared__ float ws[8];
  int wv = tid >> 6, l = tid & 63;
  if (l == 0) { ws[wv] = s; ws[4 + wv] = sq; }
  __syncthreads();
  s = ws[0] + ws[1] + ws[2] + ws[3];
  sq = ws[4] + ws[5] + ws[6] + ws[7];
  float mean = s * (1.0f / 1024.0f);
  float var = sq * (1.0f / 1024.0f) - mean * mean;
  float rs = rsqrtf(var + 1e-5f);
  float4 gv = ((const float4*)g)[tid];
  float4 bv = ((const float4*)bt)[tid];
  float4 y;
  y.x = (v.x - mean) * rs * gv.x + bv.x;
  y.y = (v.y - mean) * rs * gv.y + bv.y;
  y.z = (v.z - mean) * rs * gv.z + bv.z;
  y.w = (v.w - mean) * rs * gv.w + bv.w;
  ((float4*)(sf + row * 1024))[tid] = y;
  u16x4 yb = { f2bf(y.x), f2bf(y.y), f2bf(y.z), f2bf(y.w) };
  ((u16x4*)(sb + row * 1024))[tid] = yb;
}

__global__ __launch_bounds__(256) void ln2_kernel(const float* __restrict__ skip,
                                                  const float* __restrict__ fcc,
                                                  const float* __restrict__ g,
                                                  const float* __restrict__ bt,
                                                  const float* __restrict__ x,
                                                  const float* __restrict__ alphap,
                                                  float* __restrict__ out) {
  const int row = blockIdx.x, tid = threadIdx.x;
  float4 sv = ((const float4*)(skip + row * 1024))[tid];
  float4 fv = ((const float4*)(fcc + row * 1024))[tid];
  float4 v = {sv.x + fv.x, sv.y + fv.y, sv.z + fv.z, sv.w + fv.w};
  float s = v.x + v.y + v.z + v.w;
  float sq = v.x * v.x + v.y * v.y + v.z * v.z + v.w * v.w;
#pragma unroll
  for (int off = 1; off < 64; off <<= 1) { s += __shfl_xor(s, off); sq += __shfl_xor(sq, off); }
  __shared__ float ws[8];
  int wv = tid >> 6, l = tid & 63;
  if (l == 0) { ws[wv] = s; ws[4 + wv] = sq; }
  __syncthreads();
  s = ws[0] + ws[1] + ws[2] + ws[3];
  sq = ws[4] + ws[5] + ws[6] + ws[7];
  float mean = s * (1.0f / 1024.0f);
  float var = sq * (1.0f / 1024.0f) - mean * mean;
  float rs = rsqrtf(var + 1e-5f);
  float4 gv = ((const float4*)g)[tid];
  float4 bv = ((const float4*)bt)[tid];
  float alpha = alphap[0];
  float beta = 1.0f - alpha;
  float4 xv = ((const float4*)(x + row * 1024))[tid];
  float4 y;
  y.x = xv.x * alpha + ((v.x - mean) * rs * gv.x + bv.x) * beta;
  y.y = xv.y * alpha + ((v.y - mean) * rs * gv.y + bv.y) * beta;
  y.z = xv.z * alpha + ((v.z - mean) * rs * gv.z + bv.z) * beta;
  y.w = xv.w * alpha + ((v.w - mean) * rs * gv.w + bv.w) * beta;
  ((float4*)(out + row * 1024))[tid] = y;
}

// ---------------- launch ----------------
extern "C" void kernel_launch(void* const* d_in, const int* in_sizes, int n_in,
                              void* d_out, int out_size, void* d_ws, size_t ws_size,
                              hipStream_t stream) {
  const float* x  = (const float*)d_in[0];
  const int* mask = (const int*)d_in[1];
  const float* Wq = (const float*)d_in[2];
  const float* bq = (const float*)d_in[3];
  const float* Wk = (const float*)d_in[4];
  const float* bk = (const float*)d_in[5];
  const float* Wv = (const float*)d_in[6];
  const float* bv = (const float*)d_in[7];
  const float* Wo = (const float*)d_in[8];
  const float* bo = (const float*)d_in[9];
  const float* g1 = (const float*)d_in[10];
  const float* b1 = (const float*)d_in[11];
  const float* Wf = (const float*)d_in[12];
  const float* bf = (const float*)d_in[13];
  const float* g2 = (const float*)d_in[14];
  const float* b2 = (const float*)d_in[15];
  const float* alpha = (const float*)d_in[16];
  float* out = (float*)d_out;

  char* ws = (char*)d_ws;
  size_t off = 0;
  unsigned short* xb   = (unsigned short*)(ws + off); off += 8388608;   // 4096x1024 bf16
  unsigned short* Wqkv = (unsigned short*)(ws + off); off += 6291456;   // 3072x1024 bf16
  unsigned short* Wob  = (unsigned short*)(ws + off); off += 2097152;
  unsigned short* Wfb  = (unsigned short*)(ws + off); off += 2097152;
  float* bcat          = (float*)(ws + off);          off += 12288;
  float* maf           = (float*)(ws + off);          off += 16384;     // maskadd [4][1024]
  unsigned short* qkvb = (unsigned short*)(ws + off); off += 25165824;  // 4096x3072 bf16
  unsigned short* attb = (unsigned short*)(ws + off); off += 8388608;
  float* tmp           = (float*)(ws + off);          off += 16777216;  // VT (attn) -> att@Wo -> fcc
  float* s1f           = (float*)(ws + off);          off += 16777216;
  unsigned short* s1b  = (unsigned short*)(ws + off); off += 8388608;

  unsigned short* VT = (unsigned short*)tmp;  // 8MB, used only during attention

  // fused casts + prep
  cast_all<<<9216, 256, 0, stream>>>(x, Wq, Wk, Wv, Wo, Wf, xb, Wqkv, Wob, Wfb);
  maskadd_kernel<<<16, 256, 0, stream>>>(mask, maf);
  hipMemcpyAsync(bcat,        bq, 4096, hipMemcpyDeviceToDevice, stream);
  hipMemcpyAsync(bcat + 1024, bk, 4096, hipMemcpyDeviceToDevice, stream);
  hipMemcpyAsync(bcat + 2048, bv, 4096, hipMemcpyDeviceToDevice, stream);

  // fused QKV GEMM: [4096,1024] x [3072,1024]^T -> bf16 [4096,3072]
  gemm_lds<0><<<dim3(32, 24), 256, 0, stream>>>(xb, Wqkv, bcat, qkvb, 4096, 3072, 1024);

  // V transpose -> VT[(bh*64+d)][k]
  vtrans_kernel<<<dim3(64, 16), 256, 0, stream>>>(qkvb, VT);

  // attention -> att bf16 [4096,1024]
  attn6_kernel<<<dim3(64, 8), 256, 0, stream>>>(qkvb, VT, maf, attb);

  // O projection -> f32 tmp
  gemm_lds<1><<<dim3(32, 8), 256, 0, stream>>>(attb, Wob, bo, tmp, 4096, 1024, 1024);

  // LN1: skip1 = LN(x + tmp); emits f32 + bf16
  ln1_kernel<<<4096, 256, 0, stream>>>(x, tmp, g1, b1, s1f, s1b);

  // FF GEMM + exact GELU -> f32 (reuse tmp)
  gemm_lds<2><<<dim3(32, 8), 256, 0, stream>>>(s1b, Wfb, bf, tmp, 4096, 1024, 1024);

  // LN2 + final mix
  ln2_kernel<<<4096, 256, 0, stream>>>(s1f, tmp, g2, b2, x, alpha, out);
}